// Round 1
// baseline (477.916 us; speedup 1.0000x reference)
//
#include <hip/hip_runtime.h>
#include <hip/hip_bf16.h>
#include <math.h>

constexpr int NB   = 4;
constexpr int SEQ  = 2048;
constexpr int DM   = 1024;
constexpr int NH   = 16;
constexpr int DH2  = 64;
constexpr int NROWS = NB * SEQ; // 8192

typedef __attribute__((ext_vector_type(8))) short bf16x8;
typedef __attribute__((ext_vector_type(4))) float f32x4;
typedef __attribute__((ext_vector_type(4))) short short4v;

__device__ __forceinline__ unsigned short f2bf(float f) {
  __hip_bfloat16 h = __float2bfloat16(f);
  return *reinterpret_cast<unsigned short*>(&h);
}

__device__ __forceinline__ f32x4 mfma16(bf16x8 a, bf16x8 b, f32x4 c) {
  return __builtin_amdgcn_mfma_f32_16x16x32_bf16(a, b, c, 0, 0, 0);
}

__device__ __forceinline__ void gload_lds16(const void* g, void* l) {
  __builtin_amdgcn_global_load_lds(
      (const __attribute__((address_space(1))) void*)g,
      (__attribute__((address_space(3))) void*)l, 16, 0, 0);
}

// ---------------- cast f32 -> bf16 ----------------
__global__ void cast_kernel(const float* __restrict__ in,
                            unsigned short* __restrict__ out, int n4) {
  int i = blockIdx.x * blockDim.x + threadIdx.x;
  int stride = gridDim.x * blockDim.x;
  for (int idx = i; idx < n4; idx += stride) {
    float4 v = reinterpret_cast<const float4*>(in)[idx];
    ushort4 o;
    o.x = f2bf(v.x); o.y = f2bf(v.y); o.z = f2bf(v.z); o.w = f2bf(v.w);
    reinterpret_cast<ushort4*>(out)[idx] = o;
  }
}

// ---------------- rope table: tab[s*32+i] = (cos, sin)(pos[s]*10000^(-i/32)) ----
__global__ void rope_table_kernel(float2* __restrict__ tab, const int* __restrict__ pos) {
  int idx = blockIdx.x * blockDim.x + threadIdx.x;
  if (idx >= SEQ * 32) return;
  int s = idx >> 5, i = idx & 31;
  float inv = powf(10000.0f, -(float)i * (1.0f / 32.0f));
  float ang = (float)pos[s] * inv;
  tab[idx] = make_float2(cosf(ang), sinf(ang));
}

// ---------------- GEMM: C = A @ B^T, A [M][1024] bf16, B [1024][1024] bf16 ----
// MODE 0: f32 out [M][DM]; MODE 1: bf16 out to [B,H,S,dh] with RoPE; MODE 2: same, no RoPE.
template<int MODE>
__global__ __launch_bounds__(256)
void gemm_bt(const unsigned short* __restrict__ Ag,
             const unsigned short* __restrict__ Bg,
             void* __restrict__ Cout,
             const float2* __restrict__ tab)
{
  constexpr int K = DM;
  __shared__ unsigned short As[128 * 32];
  __shared__ unsigned short Bs[128 * 32];
  const int tid = threadIdx.x;
  const int w = tid >> 6, lane = tid & 63;
  const int wr = w >> 1, wc = w & 1;
  const int r = lane & 15, g = lane >> 4;
  const int rowTile = blockIdx.x, colTile = blockIdx.y;
  const unsigned short* Abase = Ag + (size_t)rowTile * 128 * K;
  const unsigned short* Bbase = Bg + (size_t)colTile * 128 * K;

  f32x4 acc[4][4];
#pragma unroll
  for (int m = 0; m < 4; ++m)
#pragma unroll
    for (int n = 0; n < 4; ++n) acc[m][n] = f32x4{0.f, 0.f, 0.f, 0.f};

  const int e0 = w * 1024 + lane * 8; // chunk (w*2) elem base

  for (int k0 = 0; k0 < K; k0 += 32) {
#pragma unroll
    for (int c = 0; c < 2; ++c) {
      int e = e0 + c * 512;
      int trow = e >> 5, tcol = e & 31;
      gload_lds16(Abase + (size_t)trow * K + k0 + tcol, As + (w * 2 + c) * 512);
      gload_lds16(Bbase + (size_t)trow * K + k0 + tcol, Bs + (w * 2 + c) * 512);
    }
    __syncthreads();
    bf16x8 a[4], b[4];
#pragma unroll
    for (int m = 0; m < 4; ++m)
      a[m] = *reinterpret_cast<const bf16x8*>(As + (wr * 64 + m * 16 + r) * 32 + g * 8);
#pragma unroll
    for (int n = 0; n < 4; ++n)
      b[n] = *reinterpret_cast<const bf16x8*>(Bs + (wc * 64 + n * 16 + r) * 32 + g * 8);
#pragma unroll
    for (int m = 0; m < 4; ++m)
#pragma unroll
      for (int n = 0; n < 4; ++n)
        acc[m][n] = mfma16(a[m], b[n], acc[m][n]);
    __syncthreads();
  }

  const int row0 = rowTile * 128 + wr * 64;
  const int col0 = colTile * 128 + wc * 64;
  if constexpr (MODE == 0) {
    float* C = reinterpret_cast<float*>(Cout);
#pragma unroll
    for (int m = 0; m < 4; ++m)
#pragma unroll
      for (int n = 0; n < 4; ++n)
#pragma unroll
        for (int j = 0; j < 4; ++j) {
          int rr = row0 + m * 16 + g * 4 + j;
          int cc = col0 + n * 16 + r;
          C[(size_t)rr * DM + cc] = acc[m][n][j];
        }
  } else {
    unsigned short* Ob = reinterpret_cast<unsigned short*>(Cout);
#pragma unroll
    for (int m = 0; m < 4; ++m)
#pragma unroll
      for (int n = 0; n < 4; ++n)
#pragma unroll
        for (int j = 0; j < 4; ++j) {
          int rr = row0 + m * 16 + g * 4 + j;
          int ee = col0 + n * 16 + r;
          float val = acc[m][n][j];
          if constexpr (MODE == 1) {
            float partner = __shfl_xor(val, 1);
            int dd = ee & 63;
            int sr = rr & (SEQ - 1);
            float2 cs = tab[sr * 32 + (dd >> 1)];
            val = val * cs.x + (((ee & 1) == 0) ? -partner : partner) * cs.y;
          }
          int bb = rr >> 11;
          int sr2 = rr & (SEQ - 1);
          int h = ee >> 6, d = ee & 63;
          Ob[((size_t)(bb * NH + h) * SEQ + sr2) * DH2 + d] = f2bf(val);
        }
  }
}

// ---------------- flash attention (causal), Q/K/V [B,H,S,dh] bf16 -> AO [B,S,D] bf16 ----
__global__ __launch_bounds__(256)
void flash_attn(const unsigned short* __restrict__ Qb,
                const unsigned short* __restrict__ Kb,
                const unsigned short* __restrict__ Vb,
                unsigned short* __restrict__ AO)
{
  __shared__ unsigned short Vt[64 * 40];     // V^T tile [d][kv], stride 40
  __shared__ unsigned short Pl[4][32 * 40];  // per-wave P [q][kv], stride 40
  const int tid = threadIdx.x;
  const int w = tid >> 6, lane = tid & 63;
  const int r = lane & 15, g = lane >> 4;
  const int bh = blockIdx.y;
  const int qt0 = blockIdx.x * 128;
  const int q0w = qt0 + w * 32;
  const unsigned short* Qh = Qb + (size_t)bh * SEQ * DH2;
  const unsigned short* Kh = Kb + (size_t)bh * SEQ * DH2;
  const unsigned short* Vh = Vb + (size_t)bh * SEQ * DH2;

  bf16x8 qf[2][2];
#pragma unroll
  for (int mq = 0; mq < 2; ++mq)
#pragma unroll
    for (int kk = 0; kk < 2; ++kk)
      qf[mq][kk] = *reinterpret_cast<const bf16x8*>(
          Qh + (size_t)(q0w + mq * 16 + r) * DH2 + kk * 32 + g * 8);

  f32x4 oacc[2][4];
  float m_run[2][4], l_part[2][4];
#pragma unroll
  for (int mq = 0; mq < 2; ++mq) {
#pragma unroll
    for (int nd = 0; nd < 4; ++nd) oacc[mq][nd] = f32x4{0.f, 0.f, 0.f, 0.f};
#pragma unroll
    for (int j = 0; j < 4; ++j) { m_run[mq][j] = -__builtin_inff(); l_part[mq][j] = 0.f; }
  }

  const int myTiles = q0w / 32 + 1;
  const int allTiles = qt0 / 32 + 4;
  const int kp = (tid & 15) * 2;   // kv pair for V staging
  const int db = (tid >> 4) * 4;   // 4 d-values for V staging
  unsigned short* P = Pl[w];

  for (int t = 0; t < allTiles; ++t) {
    const int kv0 = t * 32;
    __syncthreads();  // protect Vt from previous iteration's readers
    {
      const unsigned short* v0p = Vh + (size_t)(kv0 + kp) * DH2 + db;
      short4v a0 = *reinterpret_cast<const short4v*>(v0p);
      short4v a1 = *reinterpret_cast<const short4v*>(v0p + DH2);
#pragma unroll
      for (int dd = 0; dd < 4; ++dd) {
        unsigned int pk = (unsigned int)(unsigned short)a0[dd] |
                          ((unsigned int)(unsigned short)a1[dd] << 16);
        *reinterpret_cast<unsigned int*>(&Vt[(db + dd) * 40 + kp]) = pk;
      }
    }
    __syncthreads();
    if (t < myTiles) {
      f32x4 sacc[2][2];
#pragma unroll
      for (int mq = 0; mq < 2; ++mq) {
        sacc[mq][0] = f32x4{0.f, 0.f, 0.f, 0.f};
        sacc[mq][1] = f32x4{0.f, 0.f, 0.f, 0.f};
      }
#pragma unroll
      for (int kk = 0; kk < 2; ++kk) {
        bf16x8 kf0 = *reinterpret_cast<const bf16x8*>(
            Kh + (size_t)(kv0 + r) * DH2 + kk * 32 + g * 8);
        bf16x8 kf1 = *reinterpret_cast<const bf16x8*>(
            Kh + (size_t)(kv0 + 16 + r) * DH2 + kk * 32 + g * 8);
#pragma unroll
        for (int mq = 0; mq < 2; ++mq) {
          sacc[mq][0] = mfma16(qf[mq][kk], kf0, sacc[mq][0]);
          sacc[mq][1] = mfma16(qf[mq][kk], kf1, sacc[mq][1]);
        }
      }
      const bool diag = (t == myTiles - 1);
#pragma unroll
      for (int mq = 0; mq < 2; ++mq)
#pragma unroll
        for (int nk = 0; nk < 2; ++nk)
#pragma unroll
          for (int j = 0; j < 4; ++j) {
            float sv = sacc[mq][nk][j] * 0.125f;
            if (diag) {
              int qg = q0w + mq * 16 + g * 4 + j;
              int kg = kv0 + nk * 16 + r;
              if (kg > qg) sv = -__builtin_inff();
            }
            sacc[mq][nk][j] = sv;
          }
      float corr[2][4];
#pragma unroll
      for (int mq = 0; mq < 2; ++mq)
#pragma unroll
        for (int j = 0; j < 4; ++j) {
          float v = fmaxf(sacc[mq][0][j], sacc[mq][1][j]);
          v = fmaxf(v, __shfl_xor(v, 1));
          v = fmaxf(v, __shfl_xor(v, 2));
          v = fmaxf(v, __shfl_xor(v, 4));
          v = fmaxf(v, __shfl_xor(v, 8));
          float mo = m_run[mq][j];
          float mn = fmaxf(mo, v);
          float cr = __expf(mo - mn);
          corr[mq][j] = cr;
          m_run[mq][j] = mn;
          float p0 = __expf(sacc[mq][0][j] - mn);
          float p1 = __expf(sacc[mq][1][j] - mn);
          l_part[mq][j] = l_part[mq][j] * cr + p0 + p1;
          sacc[mq][0][j] = p0;
          sacc[mq][1][j] = p1;
        }
#pragma unroll
      for (int mq = 0; mq < 2; ++mq)
#pragma unroll
        for (int nd = 0; nd < 4; ++nd)
#pragma unroll
          for (int j = 0; j < 4; ++j)
            oacc[mq][nd][j] *= corr[mq][j];
#pragma unroll
      for (int mq = 0; mq < 2; ++mq)
#pragma unroll
        for (int nk = 0; nk < 2; ++nk)
#pragma unroll
          for (int j = 0; j < 4; ++j)
            P[(mq * 16 + g * 4 + j) * 40 + nk * 16 + r] = f2bf(sacc[mq][nk][j]);
      bf16x8 vfr[4];
#pragma unroll
      for (int nd = 0; nd < 4; ++nd)
        vfr[nd] = *reinterpret_cast<const bf16x8*>(&Vt[(nd * 16 + r) * 40 + g * 8]);
#pragma unroll
      for (int mq = 0; mq < 2; ++mq) {
        bf16x8 pa = *reinterpret_cast<const bf16x8*>(P + (mq * 16 + r) * 40 + g * 8);
#pragma unroll
        for (int nd = 0; nd < 4; ++nd)
          oacc[mq][nd] = mfma16(pa, vfr[nd], oacc[mq][nd]);
      }
    }
  }

  const int bb = bh >> 4, h = bh & 15;
#pragma unroll
  for (int mq = 0; mq < 2; ++mq)
#pragma unroll
    for (int j = 0; j < 4; ++j) {
      float l = l_part[mq][j];
      l += __shfl_xor(l, 1);
      l += __shfl_xor(l, 2);
      l += __shfl_xor(l, 4);
      l += __shfl_xor(l, 8);
      float inv = 1.0f / l;
      int srow = q0w + mq * 16 + g * 4 + j;
#pragma unroll
      for (int nd = 0; nd < 4; ++nd) {
        int d = nd * 16 + r;
        AO[(size_t)(bb * SEQ + srow) * DM + h * DH2 + d] = f2bf(oacc[mq][nd][j] * inv);
      }
    }
}

extern "C" void kernel_launch(void* const* d_in, const int* in_sizes, int n_in,
                              void* d_out, int out_size, void* d_ws, size_t ws_size,
                              hipStream_t stream) {
  const float* x  = (const float*)d_in[0];
  const float* WQ = (const float*)d_in[1];
  const float* WK = (const float*)d_in[2];
  const float* WV = (const float*)d_in[3];
  const float* WO = (const float*)d_in[4];
  const int* pos  = (const int*)d_in[5];

  char* ws = (char*)d_ws;
  unsigned short* xb  = (unsigned short*)(ws + 0);
  unsigned short* wqb = (unsigned short*)(ws + (16u << 20));
  unsigned short* wkb = (unsigned short*)(ws + (18u << 20));
  unsigned short* wvb = (unsigned short*)(ws + (20u << 20));
  unsigned short* wob = (unsigned short*)(ws + (22u << 20));
  unsigned short* Qb  = (unsigned short*)(ws + (24u << 20));
  unsigned short* Kb  = (unsigned short*)(ws + (40u << 20));
  unsigned short* Vb  = (unsigned short*)(ws + (56u << 20));
  unsigned short* AO  = (unsigned short*)(ws + (72u << 20));
  float2* tab = (float2*)(ws + (88u << 20));

  cast_kernel<<<2048, 256, 0, stream>>>(x, xb, NROWS * DM / 4);
  cast_kernel<<<256, 256, 0, stream>>>(WQ, wqb, DM * DM / 4);
  cast_kernel<<<256, 256, 0, stream>>>(WK, wkb, DM * DM / 4);
  cast_kernel<<<256, 256, 0, stream>>>(WV, wvb, DM * DM / 4);
  cast_kernel<<<256, 256, 0, stream>>>(WO, wob, DM * DM / 4);
  rope_table_kernel<<<(SEQ * 32 + 255) / 256, 256, 0, stream>>>(tab, pos);

  dim3 gproj(NROWS / 128, DM / 128);
  gemm_bt<1><<<gproj, 256, 0, stream>>>(xb, wqb, (void*)Qb, tab);
  gemm_bt<1><<<gproj, 256, 0, stream>>>(xb, wkb, (void*)Kb, tab);
  gemm_bt<2><<<gproj, 256, 0, stream>>>(xb, wvb, (void*)Vb, nullptr);
  flash_attn<<<dim3(SEQ / 128, NB * NH), 256, 0, stream>>>(Qb, Kb, Vb, AO);
  gemm_bt<0><<<gproj, 256, 0, stream>>>(AO, wob, d_out, nullptr);
}

// Round 2
// 258.810 us; speedup vs baseline: 1.8466x; 1.8466x over previous
//
#include <hip/hip_runtime.h>
#include <hip/hip_bf16.h>
#include <math.h>

constexpr int NB   = 4;
constexpr int SEQ  = 2048;
constexpr int DM   = 1024;
constexpr int NH   = 16;
constexpr int DH2  = 64;
constexpr int NROWS = NB * SEQ; // 8192

typedef __attribute__((ext_vector_type(8))) short bf16x8;
typedef __attribute__((ext_vector_type(4))) float f32x4;

__device__ __forceinline__ unsigned short f2bf(float f) {
  __hip_bfloat16 h = __float2bfloat16(f);
  return *reinterpret_cast<unsigned short*>(&h);
}

__device__ __forceinline__ f32x4 mfma16(bf16x8 a, bf16x8 b, f32x4 c) {
  return __builtin_amdgcn_mfma_f32_16x16x32_bf16(a, b, c, 0, 0, 0);
}

__device__ __forceinline__ void gload_lds16(const void* g, void* l) {
  __builtin_amdgcn_global_load_lds(
      (const __attribute__((address_space(1))) void*)g,
      (__attribute__((address_space(3))) void*)l, 16, 0, 0);
}

// ---------------- cast f32 -> bf16 ----------------
__global__ void cast_kernel(const float* __restrict__ in,
                            unsigned short* __restrict__ out, int n4) {
  int i = blockIdx.x * blockDim.x + threadIdx.x;
  int stride = gridDim.x * blockDim.x;
  for (int idx = i; idx < n4; idx += stride) {
    float4 v = reinterpret_cast<const float4*>(in)[idx];
    ushort4 o;
    o.x = f2bf(v.x); o.y = f2bf(v.y); o.z = f2bf(v.z); o.w = f2bf(v.w);
    reinterpret_cast<ushort4*>(out)[idx] = o;
  }
}

// ---------------- rope table ----------------
__global__ void rope_table_kernel(float2* __restrict__ tab, const int* __restrict__ pos) {
  int idx = blockIdx.x * blockDim.x + threadIdx.x;
  if (idx >= SEQ * 32) return;
  int s = idx >> 5, i = idx & 31;
  float inv = powf(10000.0f, -(float)i * (1.0f / 32.0f));
  float ang = (float)pos[s] * inv;
  tab[idx] = make_float2(cosf(ang), sinf(ang));
}

// ---------------- GEMM: C = A @ B^T (unchanged, known-good) ----------------
template<int MODE>
__global__ __launch_bounds__(256)
void gemm_bt(const unsigned short* __restrict__ Ag,
             const unsigned short* __restrict__ Bg,
             void* __restrict__ Cout,
             const float2* __restrict__ tab)
{
  constexpr int K = DM;
  __shared__ unsigned short As[128 * 32];
  __shared__ unsigned short Bs[128 * 32];
  const int tid = threadIdx.x;
  const int w = tid >> 6, lane = tid & 63;
  const int wr = w >> 1, wc = w & 1;
  const int r = lane & 15, g = lane >> 4;
  const int rowTile = blockIdx.x, colTile = blockIdx.y;
  const unsigned short* Abase = Ag + (size_t)rowTile * 128 * K;
  const unsigned short* Bbase = Bg + (size_t)colTile * 128 * K;

  f32x4 acc[4][4];
#pragma unroll
  for (int m = 0; m < 4; ++m)
#pragma unroll
    for (int n = 0; n < 4; ++n) acc[m][n] = f32x4{0.f, 0.f, 0.f, 0.f};

  const int e0 = w * 1024 + lane * 8;

  for (int k0 = 0; k0 < K; k0 += 32) {
#pragma unroll
    for (int c = 0; c < 2; ++c) {
      int e = e0 + c * 512;
      int trow = e >> 5, tcol = e & 31;
      gload_lds16(Abase + (size_t)trow * K + k0 + tcol, As + (w * 2 + c) * 512);
      gload_lds16(Bbase + (size_t)trow * K + k0 + tcol, Bs + (w * 2 + c) * 512);
    }
    __syncthreads();
    bf16x8 a[4], b[4];
#pragma unroll
    for (int m = 0; m < 4; ++m)
      a[m] = *reinterpret_cast<const bf16x8*>(As + (wr * 64 + m * 16 + r) * 32 + g * 8);
#pragma unroll
    for (int n = 0; n < 4; ++n)
      b[n] = *reinterpret_cast<const bf16x8*>(Bs + (wc * 64 + n * 16 + r) * 32 + g * 8);
#pragma unroll
    for (int m = 0; m < 4; ++m)
#pragma unroll
      for (int n = 0; n < 4; ++n)
        acc[m][n] = mfma16(a[m], b[n], acc[m][n]);
    __syncthreads();
  }

  const int row0 = rowTile * 128 + wr * 64;
  const int col0 = colTile * 128 + wc * 64;
  if constexpr (MODE == 0) {
    float* C = reinterpret_cast<float*>(Cout);
#pragma unroll
    for (int m = 0; m < 4; ++m)
#pragma unroll
      for (int n = 0; n < 4; ++n)
#pragma unroll
        for (int j = 0; j < 4; ++j) {
          int rr = row0 + m * 16 + g * 4 + j;
          int cc = col0 + n * 16 + r;
          C[(size_t)rr * DM + cc] = acc[m][n][j];
        }
  } else {
    unsigned short* Ob = reinterpret_cast<unsigned short*>(Cout);
#pragma unroll
    for (int m = 0; m < 4; ++m)
#pragma unroll
      for (int n = 0; n < 4; ++n)
#pragma unroll
        for (int j = 0; j < 4; ++j) {
          int rr = row0 + m * 16 + g * 4 + j;
          int ee = col0 + n * 16 + r;
          float val = acc[m][n][j];
          if constexpr (MODE == 1) {
            float partner = __shfl_xor(val, 1);
            int dd = ee & 63;
            int sr = rr & (SEQ - 1);
            float2 cs = tab[sr * 32 + (dd >> 1)];
            val = val * cs.x + (((ee & 1) == 0) ? -partner : partner) * cs.y;
          }
          int bb = rr >> 11;
          int sr2 = rr & (SEQ - 1);
          int h = ee >> 6, d = ee & 63;
          Ob[((size_t)(bb * NH + h) * SEQ + sr2) * DH2 + d] = f2bf(val);
        }
  }
}

// ---------------- flash attention v2: KVBLK=64, dbuf V, prefetch, LPT ----------------
__global__ __launch_bounds__(256)
void flash_attn(const unsigned short* __restrict__ Qb,
                const unsigned short* __restrict__ Kb,
                const unsigned short* __restrict__ Vb,
                unsigned short* __restrict__ AO)
{
  constexpr int VST = 66;  // V^T lds row stride (shorts)
  constexpr int PST = 72;  // P lds row stride (shorts)
  __shared__ unsigned short Vt[2][64 * VST];
  __shared__ unsigned short Pl[4][32 * PST];
  const int tid = threadIdx.x;
  const int w = tid >> 6, lane = tid & 63;
  const int r = lane & 15, g = lane >> 4;
  const int bh = blockIdx.x;
  const int qt = (gridDim.y - 1) - blockIdx.y;  // LPT: longest blocks dispatch first
  const int qt0 = qt * 128;
  const int q0w = qt0 + w * 32;
  const unsigned short* Qh = Qb + (size_t)bh * SEQ * DH2;
  const unsigned short* Kh = Kb + (size_t)bh * SEQ * DH2;
  const unsigned short* Vh = Vb + (size_t)bh * SEQ * DH2;
  const int nT  = 2 * qt + 2;             // block-level kv tiles of 64
  const int myT = 2 * qt + 1 + (w >> 1);  // this wave's tile count

  // Q fragments (A-operand): row = q0w + mq*16 + r, cols kk*32 + g*8
  bf16x8 qf[2][2];
#pragma unroll
  for (int mq = 0; mq < 2; ++mq)
#pragma unroll
    for (int kk = 0; kk < 2; ++kk)
      qf[mq][kk] = *reinterpret_cast<const bf16x8*>(
          Qh + (size_t)(q0w + mq * 16 + r) * DH2 + kk * 32 + g * 8);

  // V staging mapping: thread loads 2 kv rows x 8 d
  const int vd  = (lane & 7) * 8;
  const int vkv = w * 16 + (lane >> 3) * 2;

  // K fragments (B-operand): row = kv0 + nk*16 + r, cols kk*32 + g*8
  bf16x8 kc[2][4], kn[2][4];
#pragma unroll
  for (int kk = 0; kk < 2; ++kk)
#pragma unroll
    for (int nk = 0; nk < 4; ++nk)
      kc[kk][nk] = *reinterpret_cast<const bf16x8*>(
          Kh + (size_t)(nk * 16 + r) * DH2 + kk * 32 + g * 8);

  // prologue: stage V tile 0
  {
    bf16x8 a0 = *reinterpret_cast<const bf16x8*>(Vh + (size_t)vkv * DH2 + vd);
    bf16x8 a1 = *reinterpret_cast<const bf16x8*>(Vh + (size_t)(vkv + 1) * DH2 + vd);
#pragma unroll
    for (int dd = 0; dd < 8; ++dd) {
      unsigned int pk = (unsigned int)(unsigned short)a0[dd] |
                        ((unsigned int)(unsigned short)a1[dd] << 16);
      *reinterpret_cast<unsigned int*>(&Vt[0][(vd + dd) * VST + vkv]) = pk;
    }
  }
  __syncthreads();

  f32x4 oacc[2][4];
  float m_run[2][4], l_part[2][4];
#pragma unroll
  for (int mq = 0; mq < 2; ++mq) {
#pragma unroll
    for (int nd = 0; nd < 4; ++nd) oacc[mq][nd] = f32x4{0.f, 0.f, 0.f, 0.f};
#pragma unroll
    for (int j = 0; j < 4; ++j) { m_run[mq][j] = -__builtin_inff(); l_part[mq][j] = 0.f; }
  }

  unsigned short* P = Pl[w];
  bf16x8 va0, va1;

  for (int t = 0; t < nT; ++t) {
    const int cur = t & 1;
    const int tn = (t + 1 < nT) ? (t + 1) : t;
    const size_t kv0n = (size_t)tn * 64;

    // issue prefetch for tile t+1 (in flight during compute below)
#pragma unroll
    for (int kk = 0; kk < 2; ++kk)
#pragma unroll
      for (int nk = 0; nk < 4; ++nk)
        kn[kk][nk] = *reinterpret_cast<const bf16x8*>(
            Kh + (kv0n + nk * 16 + r) * DH2 + kk * 32 + g * 8);
    va0 = *reinterpret_cast<const bf16x8*>(Vh + (kv0n + vkv) * DH2 + vd);
    va1 = *reinterpret_cast<const bf16x8*>(Vh + (kv0n + vkv + 1) * DH2 + vd);

    if (t < myT) {
      const int kv0 = t * 64;
      // QK^T: S[32 q][64 kv]
      f32x4 sacc[2][4];
#pragma unroll
      for (int mq = 0; mq < 2; ++mq)
#pragma unroll
        for (int nk = 0; nk < 4; ++nk) sacc[mq][nk] = f32x4{0.f, 0.f, 0.f, 0.f};
#pragma unroll
      for (int kk = 0; kk < 2; ++kk)
#pragma unroll
        for (int mq = 0; mq < 2; ++mq)
#pragma unroll
          for (int nk = 0; nk < 4; ++nk)
            sacc[mq][nk] = mfma16(qf[mq][kk], kc[kk][nk], sacc[mq][nk]);

      const bool diag = (t == myT - 1);
#pragma unroll
      for (int mq = 0; mq < 2; ++mq)
#pragma unroll
        for (int nk = 0; nk < 4; ++nk)
#pragma unroll
          for (int j = 0; j < 4; ++j) {
            float sv = sacc[mq][nk][j] * 0.125f;
            if (diag) {
              int qg = q0w + mq * 16 + g * 4 + j;
              int kg = kv0 + nk * 16 + r;
              if (kg > qg) sv = -__builtin_inff();
            }
            sacc[mq][nk][j] = sv;
          }

      float corr[2][4];
#pragma unroll
      for (int mq = 0; mq < 2; ++mq)
#pragma unroll
        for (int j = 0; j < 4; ++j) {
          float v = fmaxf(fmaxf(sacc[mq][0][j], sacc[mq][1][j]),
                          fmaxf(sacc[mq][2][j], sacc[mq][3][j]));
          v = fmaxf(v, __shfl_xor(v, 1));
          v = fmaxf(v, __shfl_xor(v, 2));
          v = fmaxf(v, __shfl_xor(v, 4));
          v = fmaxf(v, __shfl_xor(v, 8));
          float mo = m_run[mq][j];
          float mn = fmaxf(mo, v);
          float cr = __expf(mo - mn);
          corr[mq][j] = cr;
          m_run[mq][j] = mn;
          float sum = 0.f;
#pragma unroll
          for (int nk = 0; nk < 4; ++nk) {
            float p = __expf(sacc[mq][nk][j] - mn);
            sacc[mq][nk][j] = p;
            sum += p;
          }
          l_part[mq][j] = l_part[mq][j] * cr + sum;
        }
#pragma unroll
      for (int mq = 0; mq < 2; ++mq)
#pragma unroll
        for (int nd = 0; nd < 4; ++nd)
#pragma unroll
          for (int j = 0; j < 4; ++j)
            oacc[mq][nd][j] *= corr[mq][j];

      // P -> LDS (wave-private)
#pragma unroll
      for (int mq = 0; mq < 2; ++mq)
#pragma unroll
        for (int nk = 0; nk < 4; ++nk)
#pragma unroll
          for (int j = 0; j < 4; ++j)
            P[(mq * 16 + g * 4 + j) * PST + nk * 16 + r] = f2bf(sacc[mq][nk][j]);

      // PV: O += P @ V
      bf16x8 pa[2][2], vfr[4][2];
#pragma unroll
      for (int mq = 0; mq < 2; ++mq)
#pragma unroll
        for (int k2 = 0; k2 < 2; ++k2)
          pa[mq][k2] = *reinterpret_cast<const bf16x8*>(
              P + (mq * 16 + r) * PST + k2 * 32 + g * 8);
#pragma unroll
      for (int nd = 0; nd < 4; ++nd)
#pragma unroll
        for (int k2 = 0; k2 < 2; ++k2)
          vfr[nd][k2] = *reinterpret_cast<const bf16x8*>(
              &Vt[cur][(nd * 16 + r) * VST + k2 * 32 + g * 8]);
#pragma unroll
      for (int mq = 0; mq < 2; ++mq)
#pragma unroll
        for (int nd = 0; nd < 4; ++nd)
#pragma unroll
          for (int k2 = 0; k2 < 2; ++k2)
            oacc[mq][nd] = mfma16(pa[mq][k2], vfr[nd][k2], oacc[mq][nd]);
    }

    // stage next V tile into other buffer (waits prefetch vmcnt)
#pragma unroll
    for (int dd = 0; dd < 8; ++dd) {
      unsigned int pk = (unsigned int)(unsigned short)va0[dd] |
                        ((unsigned int)(unsigned short)va1[dd] << 16);
      *reinterpret_cast<unsigned int*>(&Vt[cur ^ 1][(vd + dd) * VST + vkv]) = pk;
    }
    // rotate K regs
#pragma unroll
    for (int kk = 0; kk < 2; ++kk)
#pragma unroll
      for (int nk = 0; nk < 4; ++nk) kc[kk][nk] = kn[kk][nk];
    __syncthreads();
  }

  const int bb = bh >> 4, h = bh & 15;
#pragma unroll
  for (int mq = 0; mq < 2; ++mq)
#pragma unroll
    for (int j = 0; j < 4; ++j) {
      float l = l_part[mq][j];
      l += __shfl_xor(l, 1);
      l += __shfl_xor(l, 2);
      l += __shfl_xor(l, 4);
      l += __shfl_xor(l, 8);
      float inv = 1.0f / l;
      int srow = q0w + mq * 16 + g * 4 + j;
#pragma unroll
      for (int nd = 0; nd < 4; ++nd) {
        int d = nd * 16 + r;
        AO[(size_t)(bb * SEQ + srow) * DM + h * DH2 + d] = f2bf(oacc[mq][nd][j] * inv);
      }
    }
}

extern "C" void kernel_launch(void* const* d_in, const int* in_sizes, int n_in,
                              void* d_out, int out_size, void* d_ws, size_t ws_size,
                              hipStream_t stream) {
  const float* x  = (const float*)d_in[0];
  const float* WQ = (const float*)d_in[1];
  const float* WK = (const float*)d_in[2];
  const float* WV = (const float*)d_in[3];
  const float* WO = (const float*)d_in[4];
  const int* pos  = (const int*)d_in[5];

  char* ws = (char*)d_ws;
  unsigned short* xb  = (unsigned short*)(ws + 0);
  unsigned short* wqb = (unsigned short*)(ws + (16u << 20));
  unsigned short* wkb = (unsigned short*)(ws + (18u << 20));
  unsigned short* wvb = (unsigned short*)(ws + (20u << 20));
  unsigned short* wob = (unsigned short*)(ws + (22u << 20));
  unsigned short* Qb  = (unsigned short*)(ws + (24u << 20));
  unsigned short* Kb  = (unsigned short*)(ws + (40u << 20));
  unsigned short* Vb  = (unsigned short*)(ws + (56u << 20));
  unsigned short* AO  = (unsigned short*)(ws + (72u << 20));
  float2* tab = (float2*)(ws + (88u << 20));

  cast_kernel<<<2048, 256, 0, stream>>>(x, xb, NROWS * DM / 4);
  cast_kernel<<<256, 256, 0, stream>>>(WQ, wqb, DM * DM / 4);
  cast_kernel<<<256, 256, 0, stream>>>(WK, wkb, DM * DM / 4);
  cast_kernel<<<256, 256, 0, stream>>>(WV, wvb, DM * DM / 4);
  cast_kernel<<<256, 256, 0, stream>>>(WO, wob, DM * DM / 4);
  rope_table_kernel<<<(SEQ * 32 + 255) / 256, 256, 0, stream>>>(tab, pos);

  dim3 gproj(NROWS / 128, DM / 128);
  gemm_bt<1><<<gproj, 256, 0, stream>>>(xb, wqb, (void*)Qb, tab);
  gemm_bt<1><<<gproj, 256, 0, stream>>>(xb, wkb, (void*)Kb, tab);
  gemm_bt<2><<<gproj, 256, 0, stream>>>(xb, wvb, (void*)Vb, nullptr);
  flash_attn<<<dim3(NB * NH, SEQ / 128), 256, 0, stream>>>(Qb, Kb, Vb, AO);
  gemm_bt<0><<<gproj, 256, 0, stream>>>(AO, wob, d_out, nullptr);
}

// Round 3
// 228.144 us; speedup vs baseline: 2.0948x; 1.1344x over previous
//
#include <hip/hip_runtime.h>
#include <hip/hip_bf16.h>
#include <math.h>

constexpr int NB   = 4;
constexpr int SEQ  = 2048;
constexpr int DM   = 1024;
constexpr int NH   = 16;
constexpr int DH2  = 64;
constexpr int NROWS = NB * SEQ; // 8192

typedef __attribute__((ext_vector_type(8))) short bf16x8;
typedef __attribute__((ext_vector_type(4))) short bf16x4;
typedef __attribute__((ext_vector_type(4))) float f32x4;

__device__ __forceinline__ unsigned short f2bf(float f) {
  __hip_bfloat16 h = __float2bfloat16(f);
  return *reinterpret_cast<unsigned short*>(&h);
}

__device__ __forceinline__ f32x4 mfma16(bf16x8 a, bf16x8 b, f32x4 c) {
  return __builtin_amdgcn_mfma_f32_16x16x32_bf16(a, b, c, 0, 0, 0);
}

// 16x16x16 bf16 MFMA via inline asm (ISA-listed on gfx950; A/B = 4 bf16 = 2 VGPR)
__device__ __forceinline__ f32x4 mfma16k16(bf16x4 a, bf16x4 b, f32x4 c) {
  asm("v_mfma_f32_16x16x16_bf16 %0, %1, %2, %0" : "+v"(c) : "v"(a), "v"(b));
  return c;
}

__device__ __forceinline__ void gload_lds16(const void* g, void* l) {
  __builtin_amdgcn_global_load_lds(
      (const __attribute__((address_space(1))) void*)g,
      (__attribute__((address_space(3))) void*)l, 16, 0, 0);
}

// ---------------- cast f32 -> bf16 ----------------
__global__ void cast_kernel(const float* __restrict__ in,
                            unsigned short* __restrict__ out, int n4) {
  int i = blockIdx.x * blockDim.x + threadIdx.x;
  int stride = gridDim.x * blockDim.x;
  for (int idx = i; idx < n4; idx += stride) {
    float4 v = reinterpret_cast<const float4*>(in)[idx];
    ushort4 o;
    o.x = f2bf(v.x); o.y = f2bf(v.y); o.z = f2bf(v.z); o.w = f2bf(v.w);
    reinterpret_cast<ushort4*>(out)[idx] = o;
  }
}

// ---------------- rope table ----------------
__global__ void rope_table_kernel(float2* __restrict__ tab, const int* __restrict__ pos) {
  int idx = blockIdx.x * blockDim.x + threadIdx.x;
  if (idx >= SEQ * 32) return;
  int s = idx >> 5, i = idx & 31;
  float inv = powf(10000.0f, -(float)i * (1.0f / 32.0f));
  float ang = (float)pos[s] * inv;
  tab[idx] = make_float2(cosf(ang), sinf(ang));
}

// ---------------- GEMM: C = A @ B^T (unchanged, known-good) ----------------
template<int MODE>
__global__ __launch_bounds__(256)
void gemm_bt(const unsigned short* __restrict__ Ag,
             const unsigned short* __restrict__ Bg,
             void* __restrict__ Cout,
             const float2* __restrict__ tab)
{
  constexpr int K = DM;
  __shared__ unsigned short As[128 * 32];
  __shared__ unsigned short Bs[128 * 32];
  const int tid = threadIdx.x;
  const int w = tid >> 6, lane = tid & 63;
  const int wr = w >> 1, wc = w & 1;
  const int r = lane & 15, g = lane >> 4;
  const int rowTile = blockIdx.x, colTile = blockIdx.y;
  const unsigned short* Abase = Ag + (size_t)rowTile * 128 * K;
  const unsigned short* Bbase = Bg + (size_t)colTile * 128 * K;

  f32x4 acc[4][4];
#pragma unroll
  for (int m = 0; m < 4; ++m)
#pragma unroll
    for (int n = 0; n < 4; ++n) acc[m][n] = f32x4{0.f, 0.f, 0.f, 0.f};

  const int e0 = w * 1024 + lane * 8;

  for (int k0 = 0; k0 < K; k0 += 32) {
#pragma unroll
    for (int c = 0; c < 2; ++c) {
      int e = e0 + c * 512;
      int trow = e >> 5, tcol = e & 31;
      gload_lds16(Abase + (size_t)trow * K + k0 + tcol, As + (w * 2 + c) * 512);
      gload_lds16(Bbase + (size_t)trow * K + k0 + tcol, Bs + (w * 2 + c) * 512);
    }
    __syncthreads();
    bf16x8 a[4], b[4];
#pragma unroll
    for (int m = 0; m < 4; ++m)
      a[m] = *reinterpret_cast<const bf16x8*>(As + (wr * 64 + m * 16 + r) * 32 + g * 8);
#pragma unroll
    for (int n = 0; n < 4; ++n)
      b[n] = *reinterpret_cast<const bf16x8*>(Bs + (wc * 64 + n * 16 + r) * 32 + g * 8);
#pragma unroll
    for (int m = 0; m < 4; ++m)
#pragma unroll
      for (int n = 0; n < 4; ++n)
        acc[m][n] = mfma16(a[m], b[n], acc[m][n]);
    __syncthreads();
  }

  const int row0 = rowTile * 128 + wr * 64;
  const int col0 = colTile * 128 + wc * 64;
  if constexpr (MODE == 0) {
    float* C = reinterpret_cast<float*>(Cout);
#pragma unroll
    for (int m = 0; m < 4; ++m)
#pragma unroll
      for (int n = 0; n < 4; ++n)
#pragma unroll
        for (int j = 0; j < 4; ++j) {
          int rr = row0 + m * 16 + g * 4 + j;
          int cc = col0 + n * 16 + r;
          C[(size_t)rr * DM + cc] = acc[m][n][j];
        }
  } else {
    unsigned short* Ob = reinterpret_cast<unsigned short*>(Cout);
#pragma unroll
    for (int m = 0; m < 4; ++m)
#pragma unroll
      for (int n = 0; n < 4; ++n)
#pragma unroll
        for (int j = 0; j < 4; ++j) {
          int rr = row0 + m * 16 + g * 4 + j;
          int ee = col0 + n * 16 + r;
          float val = acc[m][n][j];
          if constexpr (MODE == 1) {
            float partner = __shfl_xor(val, 1);
            int dd = ee & 63;
            int sr = rr & (SEQ - 1);
            float2 cs = tab[sr * 32 + (dd >> 1)];
            val = val * cs.x + (((ee & 1) == 0) ? -partner : partner) * cs.y;
          }
          int bb = rr >> 11;
          int sr2 = rr & (SEQ - 1);
          int h = ee >> 6, d = ee & 63;
          Ob[((size_t)(bb * NH + h) * SEQ + sr2) * DH2 + d] = f2bf(val);
        }
  }
}

// ---------------- flash attention v3: swapped QK^T, in-register P, defer-max ----
__global__ __launch_bounds__(256)
void flash_attn(const unsigned short* __restrict__ Qb,
                const unsigned short* __restrict__ Kb,
                const unsigned short* __restrict__ Vb,
                unsigned short* __restrict__ AO)
{
  constexpr int VST = 68;  // V^T lds row stride (shorts); even dword stride, b64-aligned
  __shared__ unsigned short Vt[2][64 * VST];
  const int tid = threadIdx.x;
  const int w = tid >> 6, lane = tid & 63;
  const int r = lane & 15, g = lane >> 4;
  const int pr = blockIdx.x;        // pair index 0..7
  const int bh = blockIdx.y;
  const unsigned short* Qh = Qb + (size_t)bh * SEQ * DH2;
  const unsigned short* Kh = Kb + (size_t)bh * SEQ * DH2;
  const unsigned short* Vh = Vb + (size_t)bh * SEQ * DH2;
  const int bb = bh >> 4, h = bh & 15;
  const int vd  = (lane & 7) * 8;
  const int vkv = w * 16 + (lane >> 3) * 2;
  const float C = 0.18033688f;      // 0.125 * log2(e)
  const float NEG_INF = -__builtin_inff();

  for (int ctx = 0; ctx < 2; ++ctx) {
    const int qt = ctx ? pr : (15 - pr);   // big tile first; pair sums to 34 tiles
    const int q0w = qt * 128 + w * 32;
    const int nT  = 2 * qt + 2;
    const int myT = 2 * qt + 1 + (w >> 1);

    // Q fragments (B-operand of swapped QK): col=q0w+mq*16+r, k=kk*32+g*8
    bf16x8 qf[2][2];
#pragma unroll
    for (int mq = 0; mq < 2; ++mq)
#pragma unroll
      for (int kk = 0; kk < 2; ++kk)
        qf[mq][kk] = *reinterpret_cast<const bf16x8*>(
            Qh + (size_t)(q0w + mq * 16 + r) * DH2 + kk * 32 + g * 8);

    // K fragments (A-operand): row=kv0+nk*16+r, k=kk*32+g*8
    bf16x8 kc[2][4], kn[2][4];
#pragma unroll
    for (int kk = 0; kk < 2; ++kk)
#pragma unroll
      for (int nk = 0; nk < 4; ++nk)
        kc[kk][nk] = *reinterpret_cast<const bf16x8*>(
            Kh + (size_t)(nk * 16 + r) * DH2 + kk * 32 + g * 8);

    // stage V tile 0 as V^T
    {
      bf16x8 a0 = *reinterpret_cast<const bf16x8*>(Vh + (size_t)vkv * DH2 + vd);
      bf16x8 a1 = *reinterpret_cast<const bf16x8*>(Vh + (size_t)(vkv + 1) * DH2 + vd);
#pragma unroll
      for (int dd = 0; dd < 8; ++dd) {
        unsigned int pk = (unsigned int)(unsigned short)a0[dd] |
                          ((unsigned int)(unsigned short)a1[dd] << 16);
        *reinterpret_cast<unsigned int*>(&Vt[0][(vd + dd) * VST + vkv]) = pk;
      }
    }
    __syncthreads();

    f32x4 oacc[2][4];
    float m_run[2], l_part[2];
#pragma unroll
    for (int mq = 0; mq < 2; ++mq) {
#pragma unroll
      for (int nd = 0; nd < 4; ++nd) oacc[mq][nd] = f32x4{0.f, 0.f, 0.f, 0.f};
      m_run[mq] = NEG_INF;
      l_part[mq] = 0.f;
    }

    bf16x8 va0, va1;
    for (int t = 0; t < nT; ++t) {
      const int cur = t & 1;
      const int tn = (t + 1 < nT) ? (t + 1) : t;
      const size_t kv0n = (size_t)tn * 64;

      // prefetch next K frags + V tile (in flight during compute)
#pragma unroll
      for (int kk = 0; kk < 2; ++kk)
#pragma unroll
        for (int nk = 0; nk < 4; ++nk)
          kn[kk][nk] = *reinterpret_cast<const bf16x8*>(
              Kh + (kv0n + nk * 16 + r) * DH2 + kk * 32 + g * 8);
      va0 = *reinterpret_cast<const bf16x8*>(Vh + (kv0n + vkv) * DH2 + vd);
      va1 = *reinterpret_cast<const bf16x8*>(Vh + (kv0n + vkv + 1) * DH2 + vd);

      if (t < myT) {
        const int kv0 = t * 64;
        // S^T = K @ Q^T : lane holds S[kv=nk*16+g*4+j][q=mq*16+r]
        f32x4 sacc[2][4];
#pragma unroll
        for (int mq = 0; mq < 2; ++mq)
#pragma unroll
          for (int nk = 0; nk < 4; ++nk) sacc[mq][nk] = f32x4{0.f, 0.f, 0.f, 0.f};
        __builtin_amdgcn_s_setprio(1);
#pragma unroll
        for (int kk = 0; kk < 2; ++kk)
#pragma unroll
          for (int mq = 0; mq < 2; ++mq)
#pragma unroll
            for (int nk = 0; nk < 4; ++nk)
              sacc[mq][nk] = mfma16(kc[kk][nk], qf[mq][kk], sacc[mq][nk]);
        __builtin_amdgcn_s_setprio(0);

        if (t == myT - 1) {   // causal mask on diagonal tile (raw scores)
#pragma unroll
          for (int mq = 0; mq < 2; ++mq) {
            const int qg = q0w + mq * 16 + r;
#pragma unroll
            for (int nk = 0; nk < 4; ++nk)
#pragma unroll
              for (int j = 0; j < 4; ++j) {
                int kg = kv0 + nk * 16 + g * 4 + j;
                if (kg > qg) sacc[mq][nk][j] = NEG_INF;
              }
          }
        }

        // row max (raw) per mq: in-lane 16 then cross-g
        float vmax[2];
#pragma unroll
        for (int mq = 0; mq < 2; ++mq) {
          float v0 = fmaxf(fmaxf(sacc[mq][0][0], sacc[mq][0][1]),
                           fmaxf(sacc[mq][0][2], sacc[mq][0][3]));
          float v1 = fmaxf(fmaxf(sacc[mq][1][0], sacc[mq][1][1]),
                           fmaxf(sacc[mq][1][2], sacc[mq][1][3]));
          float v2 = fmaxf(fmaxf(sacc[mq][2][0], sacc[mq][2][1]),
                           fmaxf(sacc[mq][2][2], sacc[mq][2][3]));
          float v3 = fmaxf(fmaxf(sacc[mq][3][0], sacc[mq][3][1]),
                           fmaxf(sacc[mq][3][2], sacc[mq][3][3]));
          float v = fmaxf(fmaxf(v0, v1), fmaxf(v2, v3));
          v = fmaxf(v, __shfl_xor(v, 16));
          v = fmaxf(v, __shfl_xor(v, 32));
          vmax[mq] = v;
        }

        // defer-max: skip rescale when growth <= 64 raw (=8 in exp units)
        int cskip = (vmax[0] <= m_run[0] + 64.f) && (vmax[1] <= m_run[1] + 64.f);
        if (!__all(cskip)) {
#pragma unroll
          for (int mq = 0; mq < 2; ++mq) {
            float mo = m_run[mq];
            float mn = fmaxf(mo, vmax[mq]);
            float cr = exp2f((mo - mn) * C);
            m_run[mq] = mn;
            l_part[mq] *= cr;
            float co[4];
#pragma unroll
            for (int j = 0; j < 4; ++j) co[j] = __shfl(cr, g * 4 + j);
#pragma unroll
            for (int nd = 0; nd < 4; ++nd)
#pragma unroll
              for (int j = 0; j < 4; ++j)
                oacc[mq][nd][j] *= co[j];
          }
        }

        // p = exp2(s*C - m*C), pack to A-frag of 16x16x16 (k = 4g+j)
        bf16x4 pa[2][4];
#pragma unroll
        for (int mq = 0; mq < 2; ++mq) {
          float mC = m_run[mq] * C;
          float ls = 0.f;
#pragma unroll
          for (int nk = 0; nk < 4; ++nk) {
            float p0 = exp2f(fmaf(sacc[mq][nk][0], C, -mC));
            float p1 = exp2f(fmaf(sacc[mq][nk][1], C, -mC));
            float p2 = exp2f(fmaf(sacc[mq][nk][2], C, -mC));
            float p3 = exp2f(fmaf(sacc[mq][nk][3], C, -mC));
            ls += (p0 + p1) + (p2 + p3);
            pa[mq][nk] = bf16x4{(short)f2bf(p0), (short)f2bf(p1),
                                (short)f2bf(p2), (short)f2bf(p3)};
          }
          l_part[mq] += ls;
        }

        // PV: O += P @ V via 16x16x16; B-frag = V^T[d=nd*16+r][kv=nk*16+4g+j]
        __builtin_amdgcn_s_setprio(1);
#pragma unroll
        for (int nd = 0; nd < 4; ++nd) {
          bf16x4 vb[4];
#pragma unroll
          for (int nk = 0; nk < 4; ++nk)
            vb[nk] = *reinterpret_cast<const bf16x4*>(
                &Vt[cur][(nd * 16 + r) * VST + nk * 16 + 4 * g]);
#pragma unroll
          for (int mq = 0; mq < 2; ++mq)
#pragma unroll
            for (int nk = 0; nk < 4; ++nk)
              oacc[mq][nd] = mfma16k16(pa[mq][nk], vb[nk], oacc[mq][nd]);
        }
        __builtin_amdgcn_s_setprio(0);
      }

      // stage next V tile (waits on va prefetch)
#pragma unroll
      for (int dd = 0; dd < 8; ++dd) {
        unsigned int pk = (unsigned int)(unsigned short)va0[dd] |
                          ((unsigned int)(unsigned short)va1[dd] << 16);
        *reinterpret_cast<unsigned int*>(&Vt[cur ^ 1][(vd + dd) * VST + vkv]) = pk;
      }
#pragma unroll
      for (int kk = 0; kk < 2; ++kk)
#pragma unroll
        for (int nk = 0; nk < 4; ++nk) kc[kk][nk] = kn[kk][nk];
      __syncthreads();
    }

    // epilogue: O rows q=mq*16+4g+j, cols d=nd*16+r
#pragma unroll
    for (int mq = 0; mq < 2; ++mq) {
      float l = l_part[mq];
      l += __shfl_xor(l, 16);
      l += __shfl_xor(l, 32);
#pragma unroll
      for (int j = 0; j < 4; ++j) {
        float inv = 1.0f / __shfl(l, g * 4 + j);
        int srow = q0w + mq * 16 + g * 4 + j;
#pragma unroll
        for (int nd = 0; nd < 4; ++nd) {
          int d = nd * 16 + r;
          AO[(size_t)(bb * SEQ + srow) * DM + h * DH2 + d] = f2bf(oacc[mq][nd][j] * inv);
        }
      }
    }
  }
}

extern "C" void kernel_launch(void* const* d_in, const int* in_sizes, int n_in,
                              void* d_out, int out_size, void* d_ws, size_t ws_size,
                              hipStream_t stream) {
  const float* x  = (const float*)d_in[0];
  const float* WQ = (const float*)d_in[1];
  const float* WK = (const float*)d_in[2];
  const float* WV = (const float*)d_in[3];
  const float* WO = (const float*)d_in[4];
  const int* pos  = (const int*)d_in[5];

  char* ws = (char*)d_ws;
  unsigned short* xb  = (unsigned short*)(ws + 0);
  unsigned short* wqb = (unsigned short*)(ws + (16u << 20));
  unsigned short* wkb = (unsigned short*)(ws + (18u << 20));
  unsigned short* wvb = (unsigned short*)(ws + (20u << 20));
  unsigned short* wob = (unsigned short*)(ws + (22u << 20));
  unsigned short* Qb  = (unsigned short*)(ws + (24u << 20));
  unsigned short* Kb  = (unsigned short*)(ws + (40u << 20));
  unsigned short* Vb  = (unsigned short*)(ws + (56u << 20));
  unsigned short* AO  = (unsigned short*)(ws + (72u << 20));
  float2* tab = (float2*)(ws + (88u << 20));

  cast_kernel<<<2048, 256, 0, stream>>>(x, xb, NROWS * DM / 4);
  cast_kernel<<<256, 256, 0, stream>>>(WQ, wqb, DM * DM / 4);
  cast_kernel<<<256, 256, 0, stream>>>(WK, wkb, DM * DM / 4);
  cast_kernel<<<256, 256, 0, stream>>>(WV, wvb, DM * DM / 4);
  cast_kernel<<<256, 256, 0, stream>>>(WO, wob, DM * DM / 4);
  rope_table_kernel<<<(SEQ * 32 + 255) / 256, 256, 0, stream>>>(tab, pos);

  dim3 gproj(NROWS / 128, DM / 128);
  gemm_bt<1><<<gproj, 256, 0, stream>>>(xb, wqb, (void*)Qb, tab);
  gemm_bt<1><<<gproj, 256, 0, stream>>>(xb, wkb, (void*)Kb, tab);
  gemm_bt<2><<<gproj, 256, 0, stream>>>(xb, wvb, (void*)Vb, nullptr);
  flash_attn<<<dim3(8, NB * NH), 256, 0, stream>>>(Qb, Kb, Vb, AO);
  gemm_bt<0><<<gproj, 256, 0, stream>>>(AO, wob, d_out, nullptr);
}